// Round 21
// baseline (13861.064 us; speedup 1.0000x reference)
//
#include <hip/hip_runtime.h>
#include <math.h>

// Problem constants (reference: B,T,D,H = 32,2048,512,512)
#define BB   32
#define TT   2048
#define DD   512
#define HH   512
#define G4H  2048   // 4*H

// ---------------------------------------------------------------------------
// Phase A: xw[t_local*32 + b][col] = sum_d X[b][t0+t][d] * W[d][col] + bias[col]
// fp32 tiled GEMM: 128x128 block tile, 16 K-step, 256 threads, 8x8 microtile.
// At t0==0 also zeroes the hx tag-exchange buffer (tags stored are >=1, so
// zeroed/poisoned/leftover words can never be accepted before the real
// producer writes them).
// ---------------------------------------------------------------------------
__global__ __launch_bounds__(256, 2) void gemm_xw(
    const float* __restrict__ X, const float* __restrict__ Wm,
    const float* __restrict__ bias, float* __restrict__ xw,
    int t0, unsigned long long* __restrict__ hx)
{
    if (t0 == 0 && blockIdx.x == 0) {
        const int n = 2 * BB * HH;               // 32768 u64 slots
        const int stride = gridDim.y * 256;
        for (int i = blockIdx.y * 256 + threadIdx.x; i < n; i += stride)
            hx[i] = 0ull;
    }

    __shared__ float As[16][128];
    __shared__ float Bs[16][128];

    const int tid  = threadIdx.x;
    const int row0 = blockIdx.y * 128;   // rows: (t_local, b) t-major
    const int col0 = blockIdx.x * 128;
    const int tx = tid & 15;
    const int ty = tid >> 4;

    float acc[8][8];
    #pragma unroll
    for (int i = 0; i < 8; ++i)
        #pragma unroll
        for (int j = 0; j < 8; ++j) acc[i][j] = 0.f;

    for (int k0 = 0; k0 < DD; k0 += 16) {
        #pragma unroll
        for (int i = 0; i < 2; ++i) {
            int qa = tid + i * 256;          // 0..511 quads
            int r  = qa >> 2, kq = qa & 3;
            int grow = row0 + r;
            int b = grow & 31, tl = grow >> 5;
            const float4 a = *(const float4*)(X + ((size_t)b * TT + t0 + tl) * DD + k0 + kq * 4);
            As[kq*4+0][r] = a.x; As[kq*4+1][r] = a.y;
            As[kq*4+2][r] = a.z; As[kq*4+3][r] = a.w;

            int qb = tid + i * 256;
            int kb = qb >> 5, c4 = qb & 31;
            *(float4*)&Bs[kb][c4*4] =
                *(const float4*)(Wm + (size_t)(k0 + kb) * G4H + col0 + c4 * 4);
        }
        __syncthreads();

        #pragma unroll
        for (int k = 0; k < 16; ++k) {
            float a[8], b[8];
            #pragma unroll
            for (int i = 0; i < 8; ++i) a[i] = As[k][ty*8 + i];
            #pragma unroll
            for (int j = 0; j < 8; ++j) b[j] = Bs[k][tx*8 + j];
            #pragma unroll
            for (int i = 0; i < 8; ++i)
                #pragma unroll
                for (int j = 0; j < 8; ++j) acc[i][j] += a[i] * b[j];
        }
        __syncthreads();
    }

    #pragma unroll
    for (int i = 0; i < 8; ++i) {
        int grow = row0 + ty*8 + i;
        float* dst = xw + (size_t)grow * G4H + col0 + tx*8;
        #pragma unroll
        for (int j = 0; j < 8; j += 4) {
            float4 v;
            v.x = acc[i][j+0] + bias[col0 + tx*8 + j + 0];
            v.y = acc[i][j+1] + bias[col0 + tx*8 + j + 1];
            v.z = acc[i][j+2] + bias[col0 + tx*8 + j + 2];
            v.w = acc[i][j+3] + bias[col0 + tx*8 + j + 3];
            *(float4*)(dst + j) = v;
        }
    }
}

// ---------------------------------------------------------------------------
// Phase B: 8-wave (512-thread) persistent recurrent kernel, tagged-dataflow
// h exchange — R20 kernel (known good) with ONE change: BATCH-INTERLEAVED
// hx layout.  hx[slot][p][unit][batch 0..3]  (u64 each):
//   - a consumer lane's 4 tagged words (unit hoff, batches 0-3) are now
//     32B CONTIGUOUS -> one aligned 128B line -> ONE line-visibility event
//     per lane on the detect path (was 4 lines, 4KB apart);
//   - writer invariant preserved: block (p,q)'s four publisher waves write
//     exactly the [q*16..q*16+15]x[4] = 512B region -> each line has a
//     single producing block (no line ping-pong).
// Primitives unchanged (__hip_atomic u64, SYSTEM scope — the only scope
// with verifiable progress on this platform, R13/R14 lesson). Targeted
// lgkmcnt-only join (R20), tag-carried WAR (R19 proof) unchanged.
// ---------------------------------------------------------------------------
__global__ __launch_bounds__(512, 1) void lstm_rec(
    const float* __restrict__ W,
    const float* __restrict__ h_init,
    const float* __restrict__ xw,
    float* __restrict__ out,
    float* __restrict__ c_ws,
    unsigned long long* hx,
    int t0, int nT)
{
    __shared__ float4 wlds[128][64];    // [k>>2][col_local] = w[4k..4k+3][col]
    __shared__ float4 hb4[512];         // [k] = {h_b0,h_b1,h_b2,h_b3}; [w*64..] wave-local
    __shared__ float  red[2][8][4][64]; // [parity][kslice-wave][batch][lane]

    const int tid  = threadIdx.x;
    const int p    = blockIdx.x & 7;
    const int q    = blockIdx.x >> 3;
    const int w    = tid >> 6;          // wave id = K-slice; w<4 also = batch owner
    const int lane = tid & 63;
    const int gi   = lane >> 4;
    const int u    = lane & 15;
    const int col  = gi * HH + q * 16 + u;   // this lane's global gate column

    // One-time: stage this block's recurrent W slice into LDS, k-packed.
    {
        const int cc = tid & 63;
        const int kq = tid >> 6;
        const int cg = (cc >> 4) * HH + q * 16 + (cc & 15);  // global col of cc
        const float* Wr = W + (size_t)DD * G4H + cg;
        #pragma unroll 4
        for (int i = 0; i < 16; ++i) {
            const int k4 = i * 8 + kq;          // 0..127
            float4 v;
            v.x = Wr[(size_t)(4 * k4 + 0) * G4H];
            v.y = Wr[(size_t)(4 * k4 + 1) * G4H];
            v.z = Wr[(size_t)(4 * k4 + 2) * G4H];
            v.w = Wr[(size_t)(4 * k4 + 3) * G4H];
            wlds[k4][cc] = v;
        }
    }
    __syncthreads();

    // c state: lanes 0..15 of waves 0-3 hold c[batch 4p+w][unit q*16+lane]
    float c = 0.f;
    if (t0 > 0 && w < 4 && lane < 16)
        c = c_ws[(size_t)(4 * p + w) * HH + q * 16 + lane];

    const int hoff = w * 64 + lane;       // this lane's h element (k-slice)

    // Prologue: load xw for step 0 (batch-owner waves only).
    float xg = 0.f;
    if (w < 4)
        xg = xw[((size_t)0 * BB + 4 * p + w) * G4H + col];

    for (int t = 0; t < nT; ++t) {
        const int gt = t0 + t;

        // Prefetch next step's x-part (independent; issues first).
        float xg_next = 0.f;
        if (w < 4 && t + 1 < nT)
            xg_next = xw[((size_t)(t + 1) * BB + 4 * p + w) * G4H + col];

        // 1) h ingest via tagged dataflow: 4 words/lane, now 32B contiguous
        //    (one 128B line). Conditional per-word reload (R16 form).
        float h0v, h1v, h2v, h3v;
        if (gt == 0) {
            const float hv = h_init[hoff];
            h0v = hv; h1v = hv; h2v = hv; h3v = hv;
        } else {
            const unsigned int want = (unsigned int)gt;   // tag of h(gt-1)
            const unsigned long long* ap =
                hx + (size_t)((gt - 1) & 1) * (BB * HH) + (size_t)p * (4 * HH) + (size_t)hoff * 4;
            unsigned long long v0 = __hip_atomic_load(ap + 0, __ATOMIC_RELAXED, __HIP_MEMORY_SCOPE_SYSTEM);
            unsigned long long v1 = __hip_atomic_load(ap + 1, __ATOMIC_RELAXED, __HIP_MEMORY_SCOPE_SYSTEM);
            unsigned long long v2 = __hip_atomic_load(ap + 2, __ATOMIC_RELAXED, __HIP_MEMORY_SCOPE_SYSTEM);
            unsigned long long v3 = __hip_atomic_load(ap + 3, __ATOMIC_RELAXED, __HIP_MEMORY_SCOPE_SYSTEM);
            for (;;) {
                bool bad = false;
                if ((unsigned int)(v0 >> 32) != want) { bad = true; v0 = __hip_atomic_load(ap + 0, __ATOMIC_RELAXED, __HIP_MEMORY_SCOPE_SYSTEM); }
                if ((unsigned int)(v1 >> 32) != want) { bad = true; v1 = __hip_atomic_load(ap + 1, __ATOMIC_RELAXED, __HIP_MEMORY_SCOPE_SYSTEM); }
                if ((unsigned int)(v2 >> 32) != want) { bad = true; v2 = __hip_atomic_load(ap + 2, __ATOMIC_RELAXED, __HIP_MEMORY_SCOPE_SYSTEM); }
                if ((unsigned int)(v3 >> 32) != want) { bad = true; v3 = __hip_atomic_load(ap + 3, __ATOMIC_RELAXED, __HIP_MEMORY_SCOPE_SYSTEM); }
                if (!bad) break;
            }
            h0v = __uint_as_float((unsigned int)v0);
            h1v = __uint_as_float((unsigned int)v1);
            h2v = __uint_as_float((unsigned int)v2);
            h3v = __uint_as_float((unsigned int)v3);
        }

        // 2) Wave-local stage: ONE ds_write_b128 (unit-major, 4 batches).
        float4 hv4; hv4.x = h0v; hv4.y = h1v; hv4.z = h2v; hv4.w = h3v;
        hb4[hoff] = hv4;
        asm volatile("s_waitcnt lgkmcnt(0)" ::: "memory");
        __builtin_amdgcn_sched_barrier(0);

        // 3) K-slice dot: 16 per-lane wlds b128 + 4 broadcast b128 per j,
        //    256 FMA per lane. hb4 row r = {h_b0..h_b3} at k=r.
        const int base = w * 16;
        float a0 = 0.f, a1 = 0.f, a2 = 0.f, a3 = 0.f;
        #pragma unroll
        for (int j = 0; j < 16; ++j) {
            const float4 wv = wlds[base + j][lane];
            const float4 r0 = hb4[w * 64 + 4 * j + 0];
            const float4 r1 = hb4[w * 64 + 4 * j + 1];
            const float4 r2 = hb4[w * 64 + 4 * j + 2];
            const float4 r3 = hb4[w * 64 + 4 * j + 3];
            a0 += wv.x*r0.x; a1 += wv.x*r0.y; a2 += wv.x*r0.z; a3 += wv.x*r0.w;
            a0 += wv.y*r1.x; a1 += wv.y*r1.y; a2 += wv.y*r1.z; a3 += wv.y*r1.w;
            a0 += wv.z*r2.x; a1 += wv.z*r2.y; a2 += wv.z*r2.z; a3 += wv.z*r2.w;
            a0 += wv.w*r3.x; a1 += wv.w*r3.y; a2 += wv.w*r3.z; a3 += wv.w*r3.w;
        }

        // 4) Cross-wave reduce through parity-double-buffered red[].
        const int par = gt & 1;
        red[par][w][0][lane] = a0; red[par][w][1][lane] = a1;
        red[par][w][2][lane] = a2; red[par][w][3][lane] = a3;
        // Targeted join (R20): drain ONLY this wave's LDS writes, raw
        // barrier, fence compiler motion. Global ops stay in flight.
        asm volatile("s_waitcnt lgkmcnt(0)" ::: "memory");
        __builtin_amdgcn_s_barrier();
        __builtin_amdgcn_sched_barrier(0);

        if (w < 4) {
            float g = xg;
            #pragma unroll
            for (int s = 0; s < 8; ++s) g += red[par][s][w][lane];

            // Per-lane activation BEFORE gather: lane's own gate type only.
            float act;
            if (gi == 3) act = 1.f - 2.f / (__expf(2.f * g) + 1.f);
            else         act = 1.f / (1.f + __expf(-g));

            const int ul = lane & 15;
            const float fv = __shfl(act, ul);
            const float iv = __shfl(act, ul + 16);
            const float ov = __shfl(act, ul + 32);
            const float gv = __shfl(act, ul + 48);

            if (lane < 16) {
                c = fv * c + iv * gv;
                const float tc = 1.f - 2.f / (__expf(2.f * c) + 1.f);
                const float h = ov * tc;
                // Tagged publish (interleaved layout): unit q*16+lane,
                // batch w. WAR safety carried by the tags (R19 proof).
                const unsigned long long pk =
                    ((unsigned long long)(unsigned int)(gt + 1) << 32) |
                    (unsigned long long)__float_as_uint(h);
                __hip_atomic_store(
                    hx + (size_t)(gt & 1) * (BB * HH) + (size_t)p * (4 * HH)
                       + (size_t)(q * 16 + lane) * 4 + w,
                    pk, __ATOMIC_RELAXED, __HIP_MEMORY_SCOPE_SYSTEM);
                // Output store: not read in-kernel, off the sync path.
                out[((size_t)(4 * p + w) * TT + gt) * HH + q * 16 + lane] = h;
            }
        }

        xg = xg_next;
    }

    // Spill c state for the next chunk (kernel boundary = coherence).
    if (w < 4 && lane < 16)
        c_ws[(size_t)(4 * p + w) * HH + q * 16 + lane] = c;
}

// ---------------------------------------------------------------------------
extern "C" void kernel_launch(void* const* d_in, const int* in_sizes, int n_in,
                              void* d_out, int out_size, void* d_ws, size_t ws_size,
                              hipStream_t stream) {
    const float* x      = (const float*)d_in[0];
    // d_in[1] = input_paddings (unused)
    const float* W      = (const float*)d_in[2];
    const float* bias   = (const float*)d_in[3];
    const float* h_init = (const float*)d_in[4];
    float* out = (float*)d_out;

    // ws layout: xw (CT*32*2048*4 B) | c_ws (64 KB) | hx (256 KB)
    static const int cand[] = {2048, 1024, 512, 256, 128, 64, 32, 16, 8, 4};
    const size_t extra = 65536 + 262144;
    int CT = 4;
    for (int i = 0; i < 10; ++i) {
        if ((size_t)cand[i] * BB * G4H * 4 + extra <= ws_size) { CT = cand[i]; break; }
    }
    const size_t xw_bytes = (size_t)CT * BB * G4H * 4;
    float*              xw   = (float*)d_ws;
    float*              c_ws = (float*)((char*)d_ws + xw_bytes);
    unsigned long long* hx   = (unsigned long long*)((char*)d_ws + xw_bytes + 65536);

    for (int t0 = 0; t0 < TT; t0 += CT) {
        dim3 g(G4H / 128, CT * BB / 128);
        gemm_xw<<<g, 256, 0, stream>>>(x, W, bias, xw, t0, hx);
        lstm_rec<<<256, 512, 0, stream>>>(W, h_init, xw, out, c_ws, hx, t0, CT);
    }
}

// Round 22
// 8547.086 us; speedup vs baseline: 1.6217x; 1.6217x over previous
//
#include <hip/hip_runtime.h>
#include <math.h>

// Problem constants (reference: B,T,D,H = 32,2048,512,512)
#define BB   32
#define TT   2048
#define DD   512
#define HH   512
#define G4H  2048   // 4*H

// ---------------------------------------------------------------------------
// Phase A: xw[t_local*32 + b][col] = sum_d X[b][t0+t][d] * W[d][col] + bias[col]
// fp32 tiled GEMM: 128x128 block tile, 16 K-step, 256 threads, 8x8 microtile.
// At t0==0 also zeroes the hx tag-exchange buffer (tags stored are >=1, so
// zeroed/poisoned/leftover words can never be accepted before the real
// producer writes them).
// ---------------------------------------------------------------------------
__global__ __launch_bounds__(256, 2) void gemm_xw(
    const float* __restrict__ X, const float* __restrict__ Wm,
    const float* __restrict__ bias, float* __restrict__ xw,
    int t0, unsigned long long* __restrict__ hx)
{
    if (t0 == 0 && blockIdx.x == 0) {
        const int n = 2 * BB * HH;               // 32768 u64 slots
        const int stride = gridDim.y * 256;
        for (int i = blockIdx.y * 256 + threadIdx.x; i < n; i += stride)
            hx[i] = 0ull;
    }

    __shared__ float As[16][128];
    __shared__ float Bs[16][128];

    const int tid  = threadIdx.x;
    const int row0 = blockIdx.y * 128;   // rows: (t_local, b) t-major
    const int col0 = blockIdx.x * 128;
    const int tx = tid & 15;
    const int ty = tid >> 4;

    float acc[8][8];
    #pragma unroll
    for (int i = 0; i < 8; ++i)
        #pragma unroll
        for (int j = 0; j < 8; ++j) acc[i][j] = 0.f;

    for (int k0 = 0; k0 < DD; k0 += 16) {
        #pragma unroll
        for (int i = 0; i < 2; ++i) {
            int qa = tid + i * 256;          // 0..511 quads
            int r  = qa >> 2, kq = qa & 3;
            int grow = row0 + r;
            int b = grow & 31, tl = grow >> 5;
            const float4 a = *(const float4*)(X + ((size_t)b * TT + t0 + tl) * DD + k0 + kq * 4);
            As[kq*4+0][r] = a.x; As[kq*4+1][r] = a.y;
            As[kq*4+2][r] = a.z; As[kq*4+3][r] = a.w;

            int qb = tid + i * 256;
            int kb = qb >> 5, c4 = qb & 31;
            *(float4*)&Bs[kb][c4*4] =
                *(const float4*)(Wm + (size_t)(k0 + kb) * G4H + col0 + c4 * 4);
        }
        __syncthreads();

        #pragma unroll
        for (int k = 0; k < 16; ++k) {
            float a[8], b[8];
            #pragma unroll
            for (int i = 0; i < 8; ++i) a[i] = As[k][ty*8 + i];
            #pragma unroll
            for (int j = 0; j < 8; ++j) b[j] = Bs[k][tx*8 + j];
            #pragma unroll
            for (int i = 0; i < 8; ++i)
                #pragma unroll
                for (int j = 0; j < 8; ++j) acc[i][j] += a[i] * b[j];
        }
        __syncthreads();
    }

    #pragma unroll
    for (int i = 0; i < 8; ++i) {
        int grow = row0 + ty*8 + i;
        float* dst = xw + (size_t)grow * G4H + col0 + tx*8;
        #pragma unroll
        for (int j = 0; j < 8; j += 4) {
            float4 v;
            v.x = acc[i][j+0] + bias[col0 + tx*8 + j + 0];
            v.y = acc[i][j+1] + bias[col0 + tx*8 + j + 1];
            v.z = acc[i][j+2] + bias[col0 + tx*8 + j + 2];
            v.w = acc[i][j+3] + bias[col0 + tx*8 + j + 3];
            *(float4*)(dst + j) = v;
        }
    }
}

// ---------------------------------------------------------------------------
// Phase B: 8-wave (512-thread) persistent recurrent kernel, tagged-dataflow
// h exchange — the R20 kernel (best known: 8.62 ms total), reverted from
// R21's batch-interleaved hx layout (falsified: publisher waves wrote
// 1/4-density partial lines -> 3x WRITE_SIZE RMW traffic; writer-side
// coalescing outranks reader-side line-merging in L3 producer-consumer
// exchanges).
//
// Structure: grid 256 blocks x 8 waves. p = blockIdx%8 (batches 4p..4p+3),
// q = blockIdx/8 (units 16q..16q+15 -> 64 gate cols, col_local = lane).
// Wave w = K-slice of 64; waves 0-3 also own batch w for update/publish.
// h element = one 8B word {tag = step+1 (hi32), fp32 h (lo32)} in
// hx[2][32][512], parity-double-buffered; consumers spin on exactly the
// 4 words/lane they need (conditional per-word reload). Publish = one
// coalesced 128B line per wave.
// WAR safety carried by the tags (R19 proof): publisher X at step gt
// overwrites slot[gt&1] = h(gt-2); X's waves have tag-verified h(gt-1)
// from ALL 32 blocks, and each block's h(gt-1) publish is data-dependent
// on its complete reads of h(gt-2). No counters needed.
// Per-step join = lgkmcnt(0) + raw s_barrier + sched_barrier(0) (R20):
// global ops stay in flight across the barrier (no vmcnt drain).
// ALL cross-block traffic system-scope (L3) — the only scope with
// verifiable progress on this platform (R13/R14 lesson).
// ---------------------------------------------------------------------------
__global__ __launch_bounds__(512, 1) void lstm_rec(
    const float* __restrict__ W,
    const float* __restrict__ h_init,
    const float* __restrict__ xw,
    float* __restrict__ out,
    float* __restrict__ c_ws,
    unsigned long long* hx,
    int t0, int nT)
{
    __shared__ float4 wlds[128][64];    // [k>>2][col_local] = w[4k..4k+3][col]
    __shared__ float4 hb4[512];         // [k] = {h_b0,h_b1,h_b2,h_b3}; [w*64..] wave-local
    __shared__ float  red[2][8][4][64]; // [parity][kslice-wave][batch][lane]

    const int tid  = threadIdx.x;
    const int p    = blockIdx.x & 7;
    const int q    = blockIdx.x >> 3;
    const int w    = tid >> 6;          // wave id = K-slice; w<4 also = batch owner
    const int lane = tid & 63;
    const int gi   = lane >> 4;
    const int u    = lane & 15;
    const int col  = gi * HH + q * 16 + u;   // this lane's global gate column

    // One-time: stage this block's recurrent W slice into LDS, k-packed.
    {
        const int cc = tid & 63;
        const int kq = tid >> 6;
        const int cg = (cc >> 4) * HH + q * 16 + (cc & 15);  // global col of cc
        const float* Wr = W + (size_t)DD * G4H + cg;
        #pragma unroll 4
        for (int i = 0; i < 16; ++i) {
            const int k4 = i * 8 + kq;          // 0..127
            float4 v;
            v.x = Wr[(size_t)(4 * k4 + 0) * G4H];
            v.y = Wr[(size_t)(4 * k4 + 1) * G4H];
            v.z = Wr[(size_t)(4 * k4 + 2) * G4H];
            v.w = Wr[(size_t)(4 * k4 + 3) * G4H];
            wlds[k4][cc] = v;
        }
    }
    __syncthreads();

    // c state: lanes 0..15 of waves 0-3 hold c[batch 4p+w][unit q*16+lane]
    float c = 0.f;
    if (t0 > 0 && w < 4 && lane < 16)
        c = c_ws[(size_t)(4 * p + w) * HH + q * 16 + lane];

    const int hoff = w * 64 + lane;       // this lane's h element (k-slice)

    // Prologue: load xw for step 0 (batch-owner waves only).
    float xg = 0.f;
    if (w < 4)
        xg = xw[((size_t)0 * BB + 4 * p + w) * G4H + col];

    for (int t = 0; t < nT; ++t) {
        const int gt = t0 + t;

        // Prefetch next step's x-part (independent; issues first).
        float xg_next = 0.f;
        if (w < 4 && t + 1 < nT)
            xg_next = xw[((size_t)(t + 1) * BB + 4 * p + w) * G4H + col];

        // 1) h ingest via tagged dataflow: 4 words/lane (one per batch).
        //    Conditional per-word reload (only stragglers refetch).
        float h0v, h1v, h2v, h3v;
        if (gt == 0) {
            const float hv = h_init[hoff];
            h0v = hv; h1v = hv; h2v = hv; h3v = hv;
        } else {
            const unsigned int want = (unsigned int)gt;   // tag of h(gt-1)
            const unsigned long long* hs = hx + (size_t)((gt - 1) & 1) * (BB * HH);
            const unsigned long long* a0 = hs + (size_t)(4 * p + 0) * HH + hoff;
            const unsigned long long* a1 = hs + (size_t)(4 * p + 1) * HH + hoff;
            const unsigned long long* a2 = hs + (size_t)(4 * p + 2) * HH + hoff;
            const unsigned long long* a3 = hs + (size_t)(4 * p + 3) * HH + hoff;
            unsigned long long v0 = __hip_atomic_load(a0, __ATOMIC_RELAXED, __HIP_MEMORY_SCOPE_SYSTEM);
            unsigned long long v1 = __hip_atomic_load(a1, __ATOMIC_RELAXED, __HIP_MEMORY_SCOPE_SYSTEM);
            unsigned long long v2 = __hip_atomic_load(a2, __ATOMIC_RELAXED, __HIP_MEMORY_SCOPE_SYSTEM);
            unsigned long long v3 = __hip_atomic_load(a3, __ATOMIC_RELAXED, __HIP_MEMORY_SCOPE_SYSTEM);
            for (;;) {
                bool bad = false;
                if ((unsigned int)(v0 >> 32) != want) { bad = true; v0 = __hip_atomic_load(a0, __ATOMIC_RELAXED, __HIP_MEMORY_SCOPE_SYSTEM); }
                if ((unsigned int)(v1 >> 32) != want) { bad = true; v1 = __hip_atomic_load(a1, __ATOMIC_RELAXED, __HIP_MEMORY_SCOPE_SYSTEM); }
                if ((unsigned int)(v2 >> 32) != want) { bad = true; v2 = __hip_atomic_load(a2, __ATOMIC_RELAXED, __HIP_MEMORY_SCOPE_SYSTEM); }
                if ((unsigned int)(v3 >> 32) != want) { bad = true; v3 = __hip_atomic_load(a3, __ATOMIC_RELAXED, __HIP_MEMORY_SCOPE_SYSTEM); }
                if (!bad) break;
            }
            h0v = __uint_as_float((unsigned int)v0);
            h1v = __uint_as_float((unsigned int)v1);
            h2v = __uint_as_float((unsigned int)v2);
            h3v = __uint_as_float((unsigned int)v3);
        }

        // 2) Wave-local stage: ONE ds_write_b128 (unit-major, 4 batches).
        float4 hv4; hv4.x = h0v; hv4.y = h1v; hv4.z = h2v; hv4.w = h3v;
        hb4[hoff] = hv4;
        asm volatile("s_waitcnt lgkmcnt(0)" ::: "memory");
        __builtin_amdgcn_sched_barrier(0);

        // 3) K-slice dot: 16 per-lane wlds b128 + 4 broadcast b128 per j,
        //    256 FMA per lane. hb4 row r = {h_b0..h_b3} at k=r.
        const int base = w * 16;
        float a0 = 0.f, a1 = 0.f, a2 = 0.f, a3 = 0.f;
        #pragma unroll
        for (int j = 0; j < 16; ++j) {
            const float4 wv = wlds[base + j][lane];
            const float4 r0 = hb4[w * 64 + 4 * j + 0];
            const float4 r1 = hb4[w * 64 + 4 * j + 1];
            const float4 r2 = hb4[w * 64 + 4 * j + 2];
            const float4 r3 = hb4[w * 64 + 4 * j + 3];
            a0 += wv.x*r0.x; a1 += wv.x*r0.y; a2 += wv.x*r0.z; a3 += wv.x*r0.w;
            a0 += wv.y*r1.x; a1 += wv.y*r1.y; a2 += wv.y*r1.z; a3 += wv.y*r1.w;
            a0 += wv.z*r2.x; a1 += wv.z*r2.y; a2 += wv.z*r2.z; a3 += wv.z*r2.w;
            a0 += wv.w*r3.x; a1 += wv.w*r3.y; a2 += wv.w*r3.z; a3 += wv.w*r3.w;
        }

        // 4) Cross-wave reduce through parity-double-buffered red[].
        const int par = gt & 1;
        red[par][w][0][lane] = a0; red[par][w][1][lane] = a1;
        red[par][w][2][lane] = a2; red[par][w][3][lane] = a3;
        // Targeted join (R20): drain ONLY this wave's LDS writes, raw
        // barrier, fence compiler motion. Global ops stay in flight.
        asm volatile("s_waitcnt lgkmcnt(0)" ::: "memory");
        __builtin_amdgcn_s_barrier();
        __builtin_amdgcn_sched_barrier(0);

        if (w < 4) {
            float g = xg;
            #pragma unroll
            for (int s = 0; s < 8; ++s) g += red[par][s][w][lane];

            // Per-lane activation BEFORE gather: lane's own gate type only.
            float act;
            if (gi == 3) act = 1.f - 2.f / (__expf(2.f * g) + 1.f);
            else         act = 1.f / (1.f + __expf(-g));

            const int ul = lane & 15;
            const float fv = __shfl(act, ul);
            const float iv = __shfl(act, ul + 16);
            const float ov = __shfl(act, ul + 32);
            const float gv = __shfl(act, ul + 48);

            if (lane < 16) {
                c = fv * c + iv * gv;
                const float tc = 1.f - 2.f / (__expf(2.f * c) + 1.f);
                const float h = ov * tc;
                // Tagged publish: value+tag in one 8B relaxed system store;
                // each wave's 16 lanes form ONE coalesced 128B line.
                const unsigned long long pk =
                    ((unsigned long long)(unsigned int)(gt + 1) << 32) |
                    (unsigned long long)__float_as_uint(h);
                __hip_atomic_store(
                    hx + (size_t)(gt & 1) * (BB * HH) + (size_t)(4 * p + w) * HH + q * 16 + lane,
                    pk, __ATOMIC_RELAXED, __HIP_MEMORY_SCOPE_SYSTEM);
                // Output store: not read in-kernel, off the sync path.
                out[((size_t)(4 * p + w) * TT + gt) * HH + q * 16 + lane] = h;
            }
        }

        xg = xg_next;
    }

    // Spill c state for the next chunk (kernel boundary = coherence).
    if (w < 4 && lane < 16)
        c_ws[(size_t)(4 * p + w) * HH + q * 16 + lane] = c;
}

// ---------------------------------------------------------------------------
extern "C" void kernel_launch(void* const* d_in, const int* in_sizes, int n_in,
                              void* d_out, int out_size, void* d_ws, size_t ws_size,
                              hipStream_t stream) {
    const float* x      = (const float*)d_in[0];
    // d_in[1] = input_paddings (unused)
    const float* W      = (const float*)d_in[2];
    const float* bias   = (const float*)d_in[3];
    const float* h_init = (const float*)d_in[4];
    float* out = (float*)d_out;

    // ws layout: xw (CT*32*2048*4 B) | c_ws (64 KB) | hx (256 KB)
    static const int cand[] = {2048, 1024, 512, 256, 128, 64, 32, 16, 8, 4};
    const size_t extra = 65536 + 262144;
    int CT = 4;
    for (int i = 0; i < 10; ++i) {
        if ((size_t)cand[i] * BB * G4H * 4 + extra <= ws_size) { CT = cand[i]; break; }
    }
    const size_t xw_bytes = (size_t)CT * BB * G4H * 4;
    float*              xw   = (float*)d_ws;
    float*              c_ws = (float*)((char*)d_ws + xw_bytes);
    unsigned long long* hx   = (unsigned long long*)((char*)d_ws + xw_bytes + 65536);

    for (int t0 = 0; t0 < TT; t0 += CT) {
        dim3 g(G4H / 128, CT * BB / 128);
        gemm_xw<<<g, 256, 0, stream>>>(x, W, bias, xw, t0, hx);
        lstm_rec<<<256, 512, 0, stream>>>(W, h_init, xw, out, c_ws, hx, t0, CT);
    }
}